// Round 2
// baseline (1162.693 us; speedup 1.0000x reference)
//
#include <hip/hip_runtime.h>

#define D 64
#define BN_EPS 1e-5f

// ---------------------------------------------------------------------------
// CSR build
// ---------------------------------------------------------------------------
__global__ void hist_kernel(const int* __restrict__ dst, int E, int* __restrict__ counts) {
    int i = blockIdx.x * blockDim.x + threadIdx.x;
    if (i < E) atomicAdd(&counts[dst[i]], 1);
}

// inclusive block scan of counts; rowptr[i+1] = incl(i) (pre-offset); bsums[b] = block total
// also emits dinv[i] = rsqrt(count+1)  (self loop included)
__global__ void scan1_kernel(const int* __restrict__ counts, int N,
                             int* __restrict__ rowptr, int* __restrict__ bsums,
                             float* __restrict__ dinv) {
    __shared__ int s[256];
    int i = blockIdx.x * 256 + threadIdx.x;
    int v = (i < N) ? counts[i] : 0;
    s[threadIdx.x] = v;
    __syncthreads();
    for (int off = 1; off < 256; off <<= 1) {
        int t = (threadIdx.x >= off) ? s[threadIdx.x - off] : 0;
        __syncthreads();
        s[threadIdx.x] += t;
        __syncthreads();
    }
    if (i < N) {
        rowptr[i + 1] = s[threadIdx.x];
        dinv[i] = rsqrtf((float)(v + 1));
    }
    if (threadIdx.x == 255) bsums[blockIdx.x] = s[255];
}

// single-block exclusive scan of block sums (nb <= 512)
__global__ void scan2_kernel(const int* __restrict__ bsums, int nb, int* __restrict__ boff) {
    __shared__ int s[512];
    int v = (threadIdx.x < nb) ? bsums[threadIdx.x] : 0;
    s[threadIdx.x] = v;
    __syncthreads();
    for (int off = 1; off < 512; off <<= 1) {
        int t = (threadIdx.x >= off) ? s[threadIdx.x - off] : 0;
        __syncthreads();
        s[threadIdx.x] += t;
        __syncthreads();
    }
    if (threadIdx.x < nb) boff[threadIdx.x] = s[threadIdx.x] - v; // exclusive
}

// apply block offsets; also seed cursor = final rowptr
__global__ void scan3_kernel(int* __restrict__ rowptr, const int* __restrict__ boff, int N,
                             int* __restrict__ cursor) {
    int i = blockIdx.x * 256 + threadIdx.x;
    if (i == 0) { rowptr[0] = 0; cursor[0] = 0; }
    if (i < N) {
        int v = rowptr[i + 1] + boff[i >> 8];
        rowptr[i + 1] = v;
        if (i + 1 < N) cursor[i + 1] = v;
    }
}

__global__ void fill_kernel(const int* __restrict__ esrc, const int* __restrict__ edst, int E,
                            int* __restrict__ cursor, int* __restrict__ col) {
    int e = blockIdx.x * blockDim.x + threadIdx.x;
    if (e < E) {
        int d = edst[e];
        int p = atomicAdd(&cursor[d], 1);
        col[p] = esrc[e];
    }
}

// ---------------------------------------------------------------------------
// Per-layer kernels
// ---------------------------------------------------------------------------
__device__ __forceinline__ ushort f2bf(float x) {
    uint u = __float_as_uint(x);
    u += 0x7fffu + ((u >> 16) & 1u); // RNE
    return (ushort)(u >> 16);
}

// out_bf16[r][j] = dinv[r] * sum_k act(in[r][k]) * W[k][j];  act = BN-affine + relu (if BN)
template <bool BN>
__global__ __launch_bounds__(256) void gemm_kernel(const float* __restrict__ in,
                                                   const float* __restrict__ W,
                                                   const float* __restrict__ bnp, // scale[64],shift[64]
                                                   const float* __restrict__ dinv,
                                                   ushort* __restrict__ outb, int N) {
    __shared__ float Wl[D][D];
    for (int i = threadIdx.x; i < D * D / 4; i += 256) {
        ((float4*)&Wl[0][0])[i] = ((const float4*)W)[i];
    }
    int lane = threadIdx.x & 63;
    float scale = 1.f, shift = 0.f;
    if (BN) { scale = bnp[lane]; shift = bnp[64 + lane]; }
    __syncthreads();

    int wid = (blockIdx.x * blockDim.x + threadIdx.x) >> 6;
    int nw  = (gridDim.x * blockDim.x) >> 6;
    for (int r = wid; r < N; r += nw) {
        float v = in[r * D + lane];
        if (BN) v = fmaxf(fmaf(v, scale, shift), 0.f);
        float acc = 0.f;
#pragma unroll
        for (int k = 0; k < D; ++k) {
            float bk = __shfl(v, k);
            acc = fmaf(bk, Wl[k][lane], acc);
        }
        outb[r * D + lane] = f2bf(acc * dinv[r]);
    }
}

// one wave per node per grid-stride step; two 32-lane halves each own one edge;
// lane covers features (2j, 2j+1) as one packed uint of 2 bf16.
// out[n] = dinv[n] * (hWs[n] + sum_src hWs[src]); fused BN partial stats.
__global__ __launch_bounds__(256) void agg_kernel(const ushort* __restrict__ hWs,
                                                  const int* __restrict__ rowptr,
                                                  const int* __restrict__ col,
                                                  const float* __restrict__ dinv,
                                                  float* __restrict__ out,
                                                  float* __restrict__ partials, int N) {
    const uint* hw32 = (const uint*)hWs;
    int lane = threadIdx.x & 63;
    int wv   = threadIdx.x >> 6;
    int half = lane >> 5;
    int j    = lane & 31;
    float sx = 0.f, sy = 0.f, qx = 0.f, qy = 0.f; // BN sum / sumsq partials
    int gw = blockIdx.x * 4 + wv;
    int nw = gridDim.x * 4;
    for (int n = gw; n < N; n += nw) {
        int e0 = rowptr[n], e1 = rowptr[n + 1];
        // self row (count once: half 0 only)
        uint us = hw32[(size_t)n * 32 + j];
        float ax = 0.f, ay = 0.f;
        if (half == 0) {
            ax = __uint_as_float(us << 16);
            ay = __uint_as_float(us & 0xffff0000u);
        }
        int m = e1 - 1;
        for (int eb = e0 + half; eb < e1; eb += 8) {
            int i1 = min(eb + 2, m), i2 = min(eb + 4, m), i3 = min(eb + 6, m);
            int c0 = col[eb], c1 = col[i1], c2 = col[i2], c3 = col[i3];
            uint u0 = hw32[(size_t)c0 * 32 + j];
            uint u1 = hw32[(size_t)c1 * 32 + j];
            uint u2 = hw32[(size_t)c2 * 32 + j];
            uint u3 = hw32[(size_t)c3 * 32 + j];
            ax += __uint_as_float(u0 << 16);
            ay += __uint_as_float(u0 & 0xffff0000u);
            if (eb + 2 < e1) { ax += __uint_as_float(u1 << 16); ay += __uint_as_float(u1 & 0xffff0000u); }
            if (eb + 4 < e1) { ax += __uint_as_float(u2 << 16); ay += __uint_as_float(u2 & 0xffff0000u); }
            if (eb + 6 < e1) { ax += __uint_as_float(u3 << 16); ay += __uint_as_float(u3 & 0xffff0000u); }
        }
        // combine the two halves
        ax += __shfl(ax, lane ^ 32);
        ay += __shfl(ay, lane ^ 32);
        float dn = dinv[n];
        ax *= dn; ay *= dn;
        sx += ax; sy += ay; qx += ax * ax; qy += ay * ay;
        if (half == 0) {
            ((float2*)out)[(size_t)n * 32 + j] = make_float2(ax, ay);
        }
    }
    // block-level BN stats reduce: features 0..63 sums, 64..127 sumsq
    __shared__ float red[4][128];
    if (half == 0) {
        red[wv][2 * j]     = sx;
        red[wv][2 * j + 1] = sy;
        red[wv][64 + 2 * j]     = qx;
        red[wv][64 + 2 * j + 1] = qy;
    }
    __syncthreads();
    int t = threadIdx.x;
    if (t < 128) {
        partials[(size_t)blockIdx.x * 128 + t] = red[0][t] + red[1][t] + red[2][t] + red[3][t];
    }
}

// reduce per-block partials -> bnp (scale,shift). one block, 512 threads.
__global__ void bn_reduce_kernel(const float* __restrict__ partials, int nb,
                                 const float* __restrict__ gamma,
                                 const float* __restrict__ beta,
                                 int N, float* __restrict__ bnp) {
    __shared__ float red[4][128];
    __shared__ float tot[128];
    int t = threadIdx.x & 127;
    int q = threadIdx.x >> 7;
    float v = 0.f;
    for (int p = q; p < nb; p += 4) v += partials[(size_t)p * 128 + t];
    red[q][t] = v;
    __syncthreads();
    if (threadIdx.x < 128) tot[t] = red[0][t] + red[1][t] + red[2][t] + red[3][t];
    __syncthreads();
    if (threadIdx.x < 64) {
        int f = threadIdx.x;
        float invN = 1.f / (float)N;
        float mean = tot[f] * invN;
        float var  = tot[64 + f] * invN - mean * mean;
        float sc   = gamma[f] * rsqrtf(var + BN_EPS);
        bnp[f]      = sc;
        bnp[64 + f] = beta[f] - mean * sc;
    }
}

__global__ __launch_bounds__(256) void norm_relu_kernel(float* __restrict__ h,
                                                        const float* __restrict__ bnp, int total) {
    int i = blockIdx.x * blockDim.x + threadIdx.x;
    if (i < total) {
        int f = i & 63;
        h[i] = fmaxf(fmaf(h[i], bnp[f], bnp[64 + f]), 0.f);
    }
}

// ---------------------------------------------------------------------------
extern "C" void kernel_launch(void* const* d_in, const int* in_sizes, int n_in,
                              void* d_out, int out_size, void* d_ws, size_t ws_size,
                              hipStream_t stream) {
    const float* x      = (const float*)d_in[0];
    const int*   ei     = (const int*)d_in[1];
    const float* Ws     = (const float*)d_in[2];
    // d_in[3] = bs: cancels exactly under training-mode BatchNorm
    const float* gammas = (const float*)d_in[4];
    const float* betas  = (const float*)d_in[5];

    const int N = in_sizes[0] / D;           // 100000
    const int E = in_sizes[1] / 2;           // 1250000
    const int DEPTH = in_sizes[2] / (D * D); // 4

    const int* esrc = ei;
    const int* edst = ei + E;

    char* w = (char*)d_ws;
    size_t off = 0;
    auto alloc = [&](size_t bytes) {
        void* p = w + off;
        off = (off + bytes + 255) & ~(size_t)255;
        return p;
    };
    const int aggBlocks = 2048;
    ushort* hWs     = (ushort*)alloc((size_t)N * D * sizeof(ushort)); // 12.8 MB bf16
    int*    counts  = (int*)alloc((size_t)N * sizeof(int));
    int*    rowptr  = (int*)alloc((size_t)(N + 1) * sizeof(int));
    int*    cursor  = (int*)alloc((size_t)(N + 1) * sizeof(int));
    float*  dinv    = (float*)alloc((size_t)N * sizeof(float));
    int*    col     = (int*)alloc((size_t)E * sizeof(int));
    int*    bsums   = (int*)alloc(512 * sizeof(int));
    int*    boff    = (int*)alloc(512 * sizeof(int));
    float*  partials= (float*)alloc((size_t)aggBlocks * 128 * sizeof(float));
    float*  bnp     = (float*)alloc(128 * sizeof(float));
    float*  A       = (float*)d_out; // pre-norm h ping buffer lives in d_out

    const int nbScan = (N + 255) / 256; // 391

    // ---- degree + CSR ----
    hipMemsetAsync(counts, 0, (size_t)N * sizeof(int), stream);
    hist_kernel<<<(E + 255) / 256, 256, 0, stream>>>(edst, E, counts);
    scan1_kernel<<<nbScan, 256, 0, stream>>>(counts, N, rowptr, bsums, dinv);
    scan2_kernel<<<1, 512, 0, stream>>>(bsums, nbScan, boff);
    scan3_kernel<<<nbScan, 256, 0, stream>>>(rowptr, boff, N, cursor);
    fill_kernel<<<(E + 255) / 256, 256, 0, stream>>>(esrc, edst, E, cursor, col);

    // ---- layers ----
    const int gemmBlocks = 1024;
    for (int l = 0; l < DEPTH; ++l) {
        const float* W = Ws + (size_t)l * D * D;
        if (l == 0)
            gemm_kernel<false><<<gemmBlocks, 256, 0, stream>>>(x, W, bnp, dinv, hWs, N);
        else
            gemm_kernel<true><<<gemmBlocks, 256, 0, stream>>>(A, W, bnp, dinv, hWs, N);
        agg_kernel<<<aggBlocks, 256, 0, stream>>>(hWs, rowptr, col, dinv, A, partials, N);
        bn_reduce_kernel<<<1, 512, 0, stream>>>(partials, aggBlocks,
                                                gammas + l * D, betas + l * D, N, bnp);
    }
    // final BN + relu applied in place on d_out
    norm_relu_kernel<<<(N * D + 255) / 256, 256, 0, stream>>>(A, bnp, N * D);
}

// Round 3
// 844.034 us; speedup vs baseline: 1.3775x; 1.3775x over previous
//
#include <hip/hip_runtime.h>

#define D 64
#define BN_EPS 1e-5f

// ---------------------------------------------------------------------------
// CSR build
// ---------------------------------------------------------------------------
__global__ void hist_kernel(const int* __restrict__ dst, int E, int* __restrict__ counts) {
    int i = blockIdx.x * blockDim.x + threadIdx.x;
    if (i < E) atomicAdd(&counts[dst[i]], 1);
}

// inclusive block scan of counts; rowptr[i+1] = incl(i) (pre-offset); bsums[b] = block total
// also emits dinv[i] = rsqrt(count+1)  (self loop included)
__global__ void scan1_kernel(const int* __restrict__ counts, int N,
                             int* __restrict__ rowptr, int* __restrict__ bsums,
                             float* __restrict__ dinv) {
    __shared__ int s[256];
    int i = blockIdx.x * 256 + threadIdx.x;
    int v = (i < N) ? counts[i] : 0;
    s[threadIdx.x] = v;
    __syncthreads();
    for (int off = 1; off < 256; off <<= 1) {
        int t = (threadIdx.x >= off) ? s[threadIdx.x - off] : 0;
        __syncthreads();
        s[threadIdx.x] += t;
        __syncthreads();
    }
    if (i < N) {
        rowptr[i + 1] = s[threadIdx.x];
        dinv[i] = rsqrtf((float)(v + 1));
    }
    if (threadIdx.x == 255) bsums[blockIdx.x] = s[255];
}

// single-block exclusive scan of block sums (nb <= 512)
__global__ void scan2_kernel(const int* __restrict__ bsums, int nb, int* __restrict__ boff) {
    __shared__ int s[512];
    int v = (threadIdx.x < nb) ? bsums[threadIdx.x] : 0;
    s[threadIdx.x] = v;
    __syncthreads();
    for (int off = 1; off < 512; off <<= 1) {
        int t = (threadIdx.x >= off) ? s[threadIdx.x - off] : 0;
        __syncthreads();
        s[threadIdx.x] += t;
        __syncthreads();
    }
    if (threadIdx.x < nb) boff[threadIdx.x] = s[threadIdx.x] - v; // exclusive
}

// apply block offsets; also seed cursor = final rowptr
__global__ void scan3_kernel(int* __restrict__ rowptr, const int* __restrict__ boff, int N,
                             int* __restrict__ cursor) {
    int i = blockIdx.x * 256 + threadIdx.x;
    if (i == 0) { rowptr[0] = 0; cursor[0] = 0; }
    if (i < N) {
        int v = rowptr[i + 1] + boff[i >> 8];
        rowptr[i + 1] = v;
        if (i + 1 < N) cursor[i + 1] = v;
    }
}

__global__ void fill_kernel(const int* __restrict__ esrc, const int* __restrict__ edst, int E,
                            int* __restrict__ cursor, int* __restrict__ col) {
    int e = blockIdx.x * blockDim.x + threadIdx.x;
    if (e < E) {
        int d = edst[e];
        int p = atomicAdd(&cursor[d], 1);
        col[p] = esrc[e];
    }
}

// ---------------------------------------------------------------------------
// Per-layer kernels
// ---------------------------------------------------------------------------
__device__ __forceinline__ ushort f2bf(float x) {
    uint u = __float_as_uint(x);
    u += 0x7fffu + ((u >> 16) & 1u); // RNE
    return (ushort)(u >> 16);
}

// out_bf16[r][j] = dinv[r] * sum_k act(in[r][k]) * W[k][j];  act = BN-affine + relu (if BN)
template <bool BN>
__global__ __launch_bounds__(256) void gemm_kernel(const float* __restrict__ in,
                                                   const float* __restrict__ W,
                                                   const float* __restrict__ bnp, // scale[64],shift[64]
                                                   const float* __restrict__ dinv,
                                                   ushort* __restrict__ outb, int N) {
    __shared__ float Wl[D][D];
    for (int i = threadIdx.x; i < D * D / 4; i += 256) {
        ((float4*)&Wl[0][0])[i] = ((const float4*)W)[i];
    }
    int lane = threadIdx.x & 63;
    float scale = 1.f, shift = 0.f;
    if (BN) { scale = bnp[lane]; shift = bnp[64 + lane]; }
    __syncthreads();

    int wid = (blockIdx.x * blockDim.x + threadIdx.x) >> 6;
    int nw  = (gridDim.x * blockDim.x) >> 6;
    for (int r = wid; r < N; r += nw) {
        float v = in[r * D + lane];
        if (BN) v = fmaxf(fmaf(v, scale, shift), 0.f);
        float acc = 0.f;
#pragma unroll
        for (int k = 0; k < D; ++k) {
            float bk = __shfl(v, k);
            acc = fmaf(bk, Wl[k][lane], acc);
        }
        outb[r * D + lane] = f2bf(acc * dinv[r]);
    }
}

__device__ __forceinline__ float bflo(uint u) { return __uint_as_float(u << 16); }
__device__ __forceinline__ float bfhi(uint u) { return __uint_as_float(u & 0xffff0000u); }

// one wave per node per grid-stride step; two 32-lane halves each own alternate edges,
// unroll depth 8 (16 gathers in flight per wave); lane covers features (2j,2j+1).
// out[n] = dinv[n] * (hWs[n] + sum_src hWs[src]); fused BN stats via trailing atomics.
__global__ __launch_bounds__(256) void agg_kernel(const ushort* __restrict__ hWs,
                                                  const int* __restrict__ rowptr,
                                                  const int* __restrict__ col,
                                                  const float* __restrict__ dinv,
                                                  float* __restrict__ out,
                                                  float* __restrict__ stats, int N) {
    const uint* hw32 = (const uint*)hWs;
    int lane = threadIdx.x & 63;
    int wv   = threadIdx.x >> 6;
    int half = lane >> 5;
    int j    = lane & 31;
    float sx = 0.f, sy = 0.f, qx = 0.f, qy = 0.f; // BN sum / sumsq partials (half 0 only)
    int gw = blockIdx.x * 4 + wv;
    int nw = gridDim.x * 4;
    for (int n = gw; n < N; n += nw) {
        int e0 = rowptr[n], e1 = rowptr[n + 1];
        float dn = dinv[n];
        uint us = hw32[(size_t)n * 32 + j];
        float ax = 0.f, ay = 0.f;
        if (half == 0) { ax = bflo(us); ay = bfhi(us); }
        int m = e1 - 1;
        for (int eb = e0 + half; eb < e1; eb += 16) {
            int cc[8];
            uint uu[8];
#pragma unroll
            for (int u = 0; u < 8; ++u) cc[u] = col[min(eb + 2 * u, m)];
#pragma unroll
            for (int u = 0; u < 8; ++u) uu[u] = hw32[(size_t)cc[u] * 32 + j];
#pragma unroll
            for (int u = 0; u < 8; ++u) {
                if (eb + 2 * u < e1) { ax += bflo(uu[u]); ay += bfhi(uu[u]); }
            }
        }
        // combine the two halves
        ax += __shfl(ax, lane ^ 32);
        ay += __shfl(ay, lane ^ 32);
        ax *= dn; ay *= dn;
        if (half == 0) {
            sx += ax; sy += ay; qx += ax * ax; qy += ay * ay;
            ((float2*)out)[(size_t)n * 32 + j] = make_float2(ax, ay);
        }
    }
    // block-level BN stats: features 0..63 sums, 64..127 sumsq -> atomics into stats[128]
    __shared__ float red[4][128];
    if (half == 0) {
        red[wv][2 * j]          = sx;
        red[wv][2 * j + 1]      = sy;
        red[wv][64 + 2 * j]     = qx;
        red[wv][64 + 2 * j + 1] = qy;
    }
    __syncthreads();
    int t = threadIdx.x;
    if (t < 128) {
        atomicAdd(&stats[t], red[0][t] + red[1][t] + red[2][t] + red[3][t]);
    }
}

// stats -> bnp (scale,shift); re-zero stats for next layer. one block, 64 threads.
__global__ void bn_finalize_kernel(float* __restrict__ stats,
                                   const float* __restrict__ gamma,
                                   const float* __restrict__ beta,
                                   int N, float* __restrict__ bnp) {
    int f = threadIdx.x; // 64 threads
    float invN = 1.f / (float)N;
    float s  = stats[f];
    float s2 = stats[64 + f];
    float mean = s * invN;
    float var  = s2 * invN - mean * mean;
    float sc   = gamma[f] * rsqrtf(var + BN_EPS);
    bnp[f]      = sc;
    bnp[64 + f] = beta[f] - mean * sc;
    stats[f] = 0.f;
    stats[64 + f] = 0.f;
}

__global__ __launch_bounds__(256) void norm_relu_kernel(float4* __restrict__ h,
                                                        const float4* __restrict__ bnp4, int total4) {
    int i = blockIdx.x * blockDim.x + threadIdx.x;
    if (i < total4) {
        int f = i & 15; // float4 index within 64-feature row
        float4 v  = h[i];
        float4 sc = bnp4[f];
        float4 sh = bnp4[16 + f];
        v.x = fmaxf(fmaf(v.x, sc.x, sh.x), 0.f);
        v.y = fmaxf(fmaf(v.y, sc.y, sh.y), 0.f);
        v.z = fmaxf(fmaf(v.z, sc.z, sh.z), 0.f);
        v.w = fmaxf(fmaf(v.w, sc.w, sh.w), 0.f);
        h[i] = v;
    }
}

// ---------------------------------------------------------------------------
extern "C" void kernel_launch(void* const* d_in, const int* in_sizes, int n_in,
                              void* d_out, int out_size, void* d_ws, size_t ws_size,
                              hipStream_t stream) {
    const float* x      = (const float*)d_in[0];
    const int*   ei     = (const int*)d_in[1];
    const float* Ws     = (const float*)d_in[2];
    // d_in[3] = bs: cancels exactly under training-mode BatchNorm
    const float* gammas = (const float*)d_in[4];
    const float* betas  = (const float*)d_in[5];

    const int N = in_sizes[0] / D;           // 100000
    const int E = in_sizes[1] / 2;           // 1250000
    const int DEPTH = in_sizes[2] / (D * D); // 4

    const int* esrc = ei;
    const int* edst = ei + E;

    char* w = (char*)d_ws;
    size_t off = 0;
    auto alloc = [&](size_t bytes) {
        void* p = w + off;
        off = (off + bytes + 255) & ~(size_t)255;
        return p;
    };
    ushort* hWs    = (ushort*)alloc((size_t)N * D * sizeof(ushort)); // 12.8 MB bf16
    int*    counts = (int*)alloc((size_t)N * sizeof(int));
    int*    rowptr = (int*)alloc((size_t)(N + 1) * sizeof(int));
    int*    cursor = (int*)alloc((size_t)(N + 1) * sizeof(int));
    float*  dinv   = (float*)alloc((size_t)N * sizeof(float));
    int*    col    = (int*)alloc((size_t)E * sizeof(int));
    int*    bsums  = (int*)alloc(512 * sizeof(int));
    int*    boff   = (int*)alloc(512 * sizeof(int));
    float*  stats  = (float*)alloc(128 * sizeof(float));
    float*  bnp    = (float*)alloc(128 * sizeof(float));
    float*  A      = (float*)d_out; // pre-norm h ping buffer lives in d_out

    const int nbScan = (N + 255) / 256; // 391

    // ---- degree + CSR ----
    hipMemsetAsync(counts, 0, (size_t)N * sizeof(int), stream);
    hipMemsetAsync(stats, 0, 128 * sizeof(float), stream);
    hist_kernel<<<(E + 255) / 256, 256, 0, stream>>>(edst, E, counts);
    scan1_kernel<<<nbScan, 256, 0, stream>>>(counts, N, rowptr, bsums, dinv);
    scan2_kernel<<<1, 512, 0, stream>>>(bsums, nbScan, boff);
    scan3_kernel<<<nbScan, 256, 0, stream>>>(rowptr, boff, N, cursor);
    fill_kernel<<<(E + 255) / 256, 256, 0, stream>>>(esrc, edst, E, cursor, col);

    // ---- layers ----
    const int gemmBlocks = 1024;
    const int aggBlocks  = 2048;
    for (int l = 0; l < DEPTH; ++l) {
        const float* W = Ws + (size_t)l * D * D;
        if (l == 0)
            gemm_kernel<false><<<gemmBlocks, 256, 0, stream>>>(x, W, bnp, dinv, hWs, N);
        else
            gemm_kernel<true><<<gemmBlocks, 256, 0, stream>>>(A, W, bnp, dinv, hWs, N);
        agg_kernel<<<aggBlocks, 256, 0, stream>>>(hWs, rowptr, col, dinv, A, stats, N);
        bn_finalize_kernel<<<1, 64, 0, stream>>>(stats, gammas + l * D, betas + l * D, N, bnp);
    }
    // final BN + relu applied in place on d_out
    norm_relu_kernel<<<(N * D / 4 + 255) / 256, 256, 0, stream>>>((float4*)A, (const float4*)bnp, N * D / 4);
}

// Round 4
// 818.945 us; speedup vs baseline: 1.4197x; 1.0306x over previous
//
#include <hip/hip_runtime.h>

#define D 64
#define BN_EPS 1e-5f
#define NPART 8

// ---------------------------------------------------------------------------
// CSR build — hist/fill partitioned by dst range so each partition's scattered
// writes/atomics stay in one XCD's L2 (blockIdx%8 == XCD round-robin) and merge
// before writeback.
// ---------------------------------------------------------------------------
__global__ __launch_bounds__(256) void hist_kernel(const int* __restrict__ edst, int E, int N,
                                                   int* __restrict__ counts) {
    int part = blockIdx.x & (NPART - 1);
    int bIdx = blockIdx.x / NPART;
    int nblk = gridDim.x / NPART;
    int partN = (N + NPART - 1) / NPART;
    int nlo = part * partN;
    int nhi = min(N, nlo + partN);
    int E4 = E >> 2;
    const int4* d4 = (const int4*)edst;
    for (int i = bIdx * 256 + threadIdx.x; i < E4; i += nblk * 256) {
        int4 d = d4[i];
        if (d.x >= nlo && d.x < nhi) atomicAdd(&counts[d.x], 1);
        if (d.y >= nlo && d.y < nhi) atomicAdd(&counts[d.y], 1);
        if (d.z >= nlo && d.z < nhi) atomicAdd(&counts[d.z], 1);
        if (d.w >= nlo && d.w < nhi) atomicAdd(&counts[d.w], 1);
    }
    if (blockIdx.x == 0) {
        for (int e = (E4 << 2) + threadIdx.x; e < E; e += 256) atomicAdd(&counts[edst[e]], 1);
    }
}

// inclusive block scan of counts; rowptr[i+1] = incl(i) (pre-offset); bsums[b] = block total
// also emits dinv[i] = rsqrt(count+1)  (self loop included)
__global__ void scan1_kernel(const int* __restrict__ counts, int N,
                             int* __restrict__ rowptr, int* __restrict__ bsums,
                             float* __restrict__ dinv) {
    __shared__ int s[256];
    int i = blockIdx.x * 256 + threadIdx.x;
    int v = (i < N) ? counts[i] : 0;
    s[threadIdx.x] = v;
    __syncthreads();
    for (int off = 1; off < 256; off <<= 1) {
        int t = (threadIdx.x >= off) ? s[threadIdx.x - off] : 0;
        __syncthreads();
        s[threadIdx.x] += t;
        __syncthreads();
    }
    if (i < N) {
        rowptr[i + 1] = s[threadIdx.x];
        dinv[i] = rsqrtf((float)(v + 1));
    }
    if (threadIdx.x == 255) bsums[blockIdx.x] = s[255];
}

__global__ void scan2_kernel(const int* __restrict__ bsums, int nb, int* __restrict__ boff) {
    __shared__ int s[512];
    int v = (threadIdx.x < nb) ? bsums[threadIdx.x] : 0;
    s[threadIdx.x] = v;
    __syncthreads();
    for (int off = 1; off < 512; off <<= 1) {
        int t = (threadIdx.x >= off) ? s[threadIdx.x - off] : 0;
        __syncthreads();
        s[threadIdx.x] += t;
        __syncthreads();
    }
    if (threadIdx.x < nb) boff[threadIdx.x] = s[threadIdx.x] - v; // exclusive
}

// apply block offsets; also seed cursor = final rowptr
__global__ void scan3_kernel(int* __restrict__ rowptr, const int* __restrict__ boff, int N,
                             int* __restrict__ cursor) {
    int i = blockIdx.x * 256 + threadIdx.x;
    if (i == 0) { rowptr[0] = 0; cursor[0] = 0; }
    if (i < N) {
        int v = rowptr[i + 1] + boff[i >> 8];
        rowptr[i + 1] = v;
        if (i + 1 < N) cursor[i + 1] = v;
    }
}

__global__ __launch_bounds__(256) void fill_kernel(const int* __restrict__ esrc,
                                                   const int* __restrict__ edst, int E, int N,
                                                   int* __restrict__ cursor, int* __restrict__ col) {
    int part = blockIdx.x & (NPART - 1);
    int bIdx = blockIdx.x / NPART;
    int nblk = gridDim.x / NPART;
    int partN = (N + NPART - 1) / NPART;
    int nlo = part * partN;
    int nhi = min(N, nlo + partN);
    int E4 = E >> 2;
    const int4* d4 = (const int4*)edst;
    const int4* s4 = (const int4*)esrc;
    for (int i = bIdx * 256 + threadIdx.x; i < E4; i += nblk * 256) {
        int4 d = d4[i];
        bool mx = (d.x >= nlo) & (d.x < nhi);
        bool my = (d.y >= nlo) & (d.y < nhi);
        bool mz = (d.z >= nlo) & (d.z < nhi);
        bool mw = (d.w >= nlo) & (d.w < nhi);
        if (mx | my | mz | mw) {
            int4 s = s4[i];
            if (mx) col[atomicAdd(&cursor[d.x], 1)] = s.x;
            if (my) col[atomicAdd(&cursor[d.y], 1)] = s.y;
            if (mz) col[atomicAdd(&cursor[d.z], 1)] = s.z;
            if (mw) col[atomicAdd(&cursor[d.w], 1)] = s.w;
        }
    }
    if (blockIdx.x == 0) {
        for (int e = (E4 << 2) + threadIdx.x; e < E; e += 256) {
            int d = edst[e];
            col[atomicAdd(&cursor[d], 1)] = esrc[e];
        }
    }
}

// ---------------------------------------------------------------------------
// Per-layer kernels
// ---------------------------------------------------------------------------
__device__ __forceinline__ ushort f2bf(float x) {
    uint u = __float_as_uint(x);
    u += 0x7fffu + ((u >> 16) & 1u); // RNE
    return (ushort)(u >> 16);
}
__device__ __forceinline__ float bflo(uint u) { return __uint_as_float(u << 16); }
__device__ __forceinline__ float bfhi(uint u) { return __uint_as_float(u & 0xffff0000u); }

// out_bf16[r][j] = dinv[r] * sum_k act(in[r][k]) * W[k][j];  act = BN-affine + relu (if BN)
// BN path reads bf16 input (pre-norm h), first layer reads fp32 x.
template <bool BN>
__global__ __launch_bounds__(256) void gemm_kernel(const float* __restrict__ inF,
                                                   const ushort* __restrict__ inB,
                                                   const float* __restrict__ W,
                                                   const float* __restrict__ bnp, // scale[64],shift[64]
                                                   const float* __restrict__ dinv,
                                                   ushort* __restrict__ outb, int N) {
    __shared__ float Wl[D][D];
    for (int i = threadIdx.x; i < D * D / 4; i += 256) {
        ((float4*)&Wl[0][0])[i] = ((const float4*)W)[i];
    }
    int lane = threadIdx.x & 63;
    float scale = 1.f, shift = 0.f;
    if (BN) { scale = bnp[lane]; shift = bnp[64 + lane]; }
    __syncthreads();

    int wid = (blockIdx.x * blockDim.x + threadIdx.x) >> 6;
    int nw  = (gridDim.x * blockDim.x) >> 6;
    for (int r = wid; r < N; r += nw) {
        float v;
        if (BN) {
            v = __uint_as_float((uint)inB[r * D + lane] << 16);
            v = fmaxf(fmaf(v, scale, shift), 0.f);
        } else {
            v = inF[r * D + lane];
        }
        float acc = 0.f;
#pragma unroll
        for (int k = 0; k < D; ++k) {
            float bk = __shfl(v, k);
            acc = fmaf(bk, Wl[k][lane], acc);
        }
        outb[r * D + lane] = f2bf(acc * dinv[r]);
    }
}

// 2 nodes per wave iteration; two 32-lane halves own alternate edges, unroll 8 per
// half per node -> up to 32 gathers in flight. lane covers features (2j,2j+1).
// outB[n] (bf16 pair) = dinv[n] * (hWs[n] + sum_src hWs[src]); fused BN stats.
__global__ __launch_bounds__(256) void agg_kernel(const ushort* __restrict__ hWs,
                                                  const int* __restrict__ rowptr,
                                                  const int* __restrict__ col,
                                                  const float* __restrict__ dinv,
                                                  uint* __restrict__ outB,
                                                  float* __restrict__ stats, int N) {
    const uint* hw32 = (const uint*)hWs;
    int lane = threadIdx.x & 63;
    int wv   = threadIdx.x >> 6;
    int half = lane >> 5;
    int j    = lane & 31;
    float sx = 0.f, sy = 0.f, qx = 0.f, qy = 0.f; // BN sum / sumsq partials (half 0 only)
    int gw = blockIdx.x * 4 + wv;
    int nw = gridDim.x * 4;
    for (int n0 = gw; n0 < N; n0 += 2 * nw) {
        int n1 = n0 + nw;
        bool h1 = n1 < N;
        int e0a = rowptr[n0], e1a = rowptr[n0 + 1];
        int e0b = 0, e1b = 0;
        if (h1) { e0b = rowptr[n1]; e1b = rowptr[n1 + 1]; }
        uint usa = hw32[(size_t)n0 * 32 + j];
        uint usb = h1 ? hw32[(size_t)n1 * 32 + j] : 0u;
        float ax = 0.f, ay = 0.f, bx = 0.f, by = 0.f;
        if (half == 0) { ax = bflo(usa); ay = bfhi(usa); bx = bflo(usb); by = bfhi(usb); }
        int ebA = e0a + half, ebB = e0b + half;
        int mA = max(e1a - 1, 0), mB = max(e1b - 1, 0);
        while (ebA < e1a || ebB < e1b) {
            int cc[16]; uint uu[16];
#pragma unroll
            for (int u = 0; u < 8; ++u) {
                int ia = ebA + 2 * u;
                cc[u] = col[ia <= mA ? ia : mA];
            }
#pragma unroll
            for (int u = 0; u < 8; ++u) {
                int ib = ebB + 2 * u;
                cc[8 + u] = col[ib <= mB ? ib : mB];
            }
#pragma unroll
            for (int u = 0; u < 16; ++u) uu[u] = hw32[(size_t)cc[u] * 32 + j];
#pragma unroll
            for (int u = 0; u < 8; ++u)
                if (ebA + 2 * u < e1a) { ax += bflo(uu[u]); ay += bfhi(uu[u]); }
#pragma unroll
            for (int u = 0; u < 8; ++u)
                if (ebB + 2 * u < e1b) { bx += bflo(uu[8 + u]); by += bfhi(uu[8 + u]); }
            ebA += 16; ebB += 16;
        }
        // combine the two halves
        ax += __shfl(ax, lane ^ 32); ay += __shfl(ay, lane ^ 32);
        bx += __shfl(bx, lane ^ 32); by += __shfl(by, lane ^ 32);
        float dna = dinv[n0];
        ax *= dna; ay *= dna;
        if (half == 0) {
            sx += ax; sy += ay; qx += ax * ax; qy += ay * ay;
            outB[(size_t)n0 * 32 + j] = ((uint)f2bf(ay) << 16) | (uint)f2bf(ax);
            if (h1) {
                float dnb = dinv[n1];
                bx *= dnb; by *= dnb;
                sx += bx; sy += by; qx += bx * bx; qy += by * by;
                outB[(size_t)n1 * 32 + j] = ((uint)f2bf(by) << 16) | (uint)f2bf(bx);
            }
        }
    }
    // block-level BN stats: features 0..63 sums, 64..127 sumsq -> atomics into stats[128]
    __shared__ float red[4][128];
    if (half == 0) {
        red[wv][2 * j]          = sx;
        red[wv][2 * j + 1]      = sy;
        red[wv][64 + 2 * j]     = qx;
        red[wv][64 + 2 * j + 1] = qy;
    }
    __syncthreads();
    int t = threadIdx.x;
    if (t < 128) {
        atomicAdd(&stats[t], red[0][t] + red[1][t] + red[2][t] + red[3][t]);
    }
}

// stats -> bnp (scale,shift); re-zero stats for next layer. one block, 64 threads.
__global__ void bn_finalize_kernel(float* __restrict__ stats,
                                   const float* __restrict__ gamma,
                                   const float* __restrict__ beta,
                                   int N, float* __restrict__ bnp) {
    int f = threadIdx.x; // 64 threads
    float invN = 1.f / (float)N;
    float s  = stats[f];
    float s2 = stats[64 + f];
    float mean = s * invN;
    float var  = s2 * invN - mean * mean;
    float sc   = gamma[f] * rsqrtf(var + BN_EPS);
    bnp[f]      = sc;
    bnp[64 + f] = beta[f] - mean * sc;
    stats[f] = 0.f;
    stats[64 + f] = 0.f;
}

// final: read bf16 pre-norm h, write fp32 BN+ReLU output
__global__ __launch_bounds__(256) void norm_relu_kernel(const uint* __restrict__ B,
                                                        const float* __restrict__ bnp,
                                                        float2* __restrict__ out, int n32) {
    int i = blockIdx.x * blockDim.x + threadIdx.x;
    if (i < n32) {
        int f2 = (i & 31) * 2;
        uint u = B[i];
        float a = fmaxf(fmaf(bflo(u), bnp[f2],     bnp[64 + f2]),     0.f);
        float b = fmaxf(fmaf(bfhi(u), bnp[f2 + 1], bnp[64 + f2 + 1]), 0.f);
        out[i] = make_float2(a, b);
    }
}

// ---------------------------------------------------------------------------
extern "C" void kernel_launch(void* const* d_in, const int* in_sizes, int n_in,
                              void* d_out, int out_size, void* d_ws, size_t ws_size,
                              hipStream_t stream) {
    const float* x      = (const float*)d_in[0];
    const int*   ei     = (const int*)d_in[1];
    const float* Ws     = (const float*)d_in[2];
    // d_in[3] = bs: cancels exactly under training-mode BatchNorm
    const float* gammas = (const float*)d_in[4];
    const float* betas  = (const float*)d_in[5];

    const int N = in_sizes[0] / D;           // 100000
    const int E = in_sizes[1] / 2;           // 1250000
    const int DEPTH = in_sizes[2] / (D * D); // 4

    const int* esrc = ei;
    const int* edst = ei + E;

    char* w = (char*)d_ws;
    size_t off = 0;
    auto alloc = [&](size_t bytes) {
        void* p = w + off;
        off = (off + bytes + 255) & ~(size_t)255;
        return p;
    };
    ushort* hWs    = (ushort*)alloc((size_t)N * D * sizeof(ushort)); // 12.8 MB bf16 (dinv-scaled h@W)
    uint*   B      = (uint*)alloc((size_t)N * (D / 2) * sizeof(uint)); // 12.8 MB bf16 pre-norm h
    int*    counts = (int*)alloc((size_t)N * sizeof(int));
    int*    rowptr = (int*)alloc((size_t)(N + 1) * sizeof(int));
    int*    cursor = (int*)alloc((size_t)(N + 1) * sizeof(int));
    float*  dinv   = (float*)alloc((size_t)N * sizeof(float));
    int*    col    = (int*)alloc((size_t)E * sizeof(int));
    int*    bsums  = (int*)alloc(512 * sizeof(int));
    int*    boff   = (int*)alloc(512 * sizeof(int));
    float*  stats  = (float*)alloc(128 * sizeof(float));
    float*  bnp    = (float*)alloc(128 * sizeof(float));

    const int nbScan = (N + 255) / 256; // 391

    // ---- degree + CSR ----
    hipMemsetAsync(counts, 0, (size_t)N * sizeof(int), stream);
    hipMemsetAsync(stats, 0, 128 * sizeof(float), stream);
    hist_kernel<<<1024, 256, 0, stream>>>(edst, E, N, counts);
    scan1_kernel<<<nbScan, 256, 0, stream>>>(counts, N, rowptr, bsums, dinv);
    scan2_kernel<<<1, 512, 0, stream>>>(bsums, nbScan, boff);
    scan3_kernel<<<nbScan, 256, 0, stream>>>(rowptr, boff, N, cursor);
    fill_kernel<<<1024, 256, 0, stream>>>(esrc, edst, E, N, cursor, col);

    // ---- layers ----
    const int gemmBlocks = 1024;
    const int aggBlocks  = 2048;
    for (int l = 0; l < DEPTH; ++l) {
        const float* W = Ws + (size_t)l * D * D;
        if (l == 0)
            gemm_kernel<false><<<gemmBlocks, 256, 0, stream>>>(x, (const ushort*)B, W, bnp, dinv, hWs, N);
        else
            gemm_kernel<true><<<gemmBlocks, 256, 0, stream>>>(x, (const ushort*)B, W, bnp, dinv, hWs, N);
        agg_kernel<<<aggBlocks, 256, 0, stream>>>(hWs, rowptr, col, dinv, B, stats, N);
        bn_finalize_kernel<<<1, 64, 0, stream>>>(stats, gammas + l * D, betas + l * D, N, bnp);
    }
    // final BN + relu: bf16 B -> fp32 d_out
    norm_relu_kernel<<<(N * (D / 2) + 255) / 256, 256, 0, stream>>>(B, bnp, (float2*)d_out, N * (D / 2));
}

// Round 5
// 619.189 us; speedup vs baseline: 1.8778x; 1.3226x over previous
//
#include <hip/hip_runtime.h>

#define D 64
#define BN_EPS 1e-5f
#define NPART 8

// ---------------------------------------------------------------------------
// CSR build — hist/fill partitioned by dst range so each partition's scattered
// writes/atomics stay in one XCD's L2 (blockIdx%8 == XCD round-robin) and merge
// before writeback.
// ---------------------------------------------------------------------------
__global__ __launch_bounds__(256) void hist_kernel(const int* __restrict__ edst, int E, int N,
                                                   int* __restrict__ counts) {
    int part = blockIdx.x & (NPART - 1);
    int bIdx = blockIdx.x / NPART;
    int nblk = gridDim.x / NPART;
    int partN = (N + NPART - 1) / NPART;
    int nlo = part * partN;
    int nhi = min(N, nlo + partN);
    int E4 = E >> 2;
    const int4* d4 = (const int4*)edst;
    for (int i = bIdx * 256 + threadIdx.x; i < E4; i += nblk * 256) {
        int4 d = d4[i];
        if (d.x >= nlo && d.x < nhi) atomicAdd(&counts[d.x], 1);
        if (d.y >= nlo && d.y < nhi) atomicAdd(&counts[d.y], 1);
        if (d.z >= nlo && d.z < nhi) atomicAdd(&counts[d.z], 1);
        if (d.w >= nlo && d.w < nhi) atomicAdd(&counts[d.w], 1);
    }
    if (blockIdx.x == 0) {
        for (int e = (E4 << 2) + threadIdx.x; e < E; e += 256) atomicAdd(&counts[edst[e]], 1);
    }
}

// inclusive block scan of counts; rowptr[i+1] = incl(i) (pre-offset); bsums[b] = block total
// also emits dinv[i] = rsqrt(count+1)  (self loop included)
__global__ void scan1_kernel(const int* __restrict__ counts, int N,
                             int* __restrict__ rowptr, int* __restrict__ bsums,
                             float* __restrict__ dinv) {
    __shared__ int s[256];
    int i = blockIdx.x * 256 + threadIdx.x;
    int v = (i < N) ? counts[i] : 0;
    s[threadIdx.x] = v;
    __syncthreads();
    for (int off = 1; off < 256; off <<= 1) {
        int t = (threadIdx.x >= off) ? s[threadIdx.x - off] : 0;
        __syncthreads();
        s[threadIdx.x] += t;
        __syncthreads();
    }
    if (i < N) {
        rowptr[i + 1] = s[threadIdx.x];
        dinv[i] = rsqrtf((float)(v + 1));
    }
    if (threadIdx.x == 255) bsums[blockIdx.x] = s[255];
}

__global__ void scan2_kernel(const int* __restrict__ bsums, int nb, int* __restrict__ boff) {
    __shared__ int s[512];
    int v = (threadIdx.x < nb) ? bsums[threadIdx.x] : 0;
    s[threadIdx.x] = v;
    __syncthreads();
    for (int off = 1; off < 512; off <<= 1) {
        int t = (threadIdx.x >= off) ? s[threadIdx.x - off] : 0;
        __syncthreads();
        s[threadIdx.x] += t;
        __syncthreads();
    }
    if (threadIdx.x < nb) boff[threadIdx.x] = s[threadIdx.x] - v; // exclusive
}

// apply block offsets; also seed cursor = final rowptr
__global__ void scan3_kernel(int* __restrict__ rowptr, const int* __restrict__ boff, int N,
                             int* __restrict__ cursor) {
    int i = blockIdx.x * 256 + threadIdx.x;
    if (i == 0) { rowptr[0] = 0; cursor[0] = 0; }
    if (i < N) {
        int v = rowptr[i + 1] + boff[i >> 8];
        rowptr[i + 1] = v;
        if (i + 1 < N) cursor[i + 1] = v;
    }
}

__global__ __launch_bounds__(256) void fill_kernel(const int* __restrict__ esrc,
                                                   const int* __restrict__ edst, int E, int N,
                                                   int* __restrict__ cursor, int* __restrict__ col) {
    int part = blockIdx.x & (NPART - 1);
    int bIdx = blockIdx.x / NPART;
    int nblk = gridDim.x / NPART;
    int partN = (N + NPART - 1) / NPART;
    int nlo = part * partN;
    int nhi = min(N, nlo + partN);
    int E4 = E >> 2;
    const int4* d4 = (const int4*)edst;
    const int4* s4 = (const int4*)esrc;
    for (int i = bIdx * 256 + threadIdx.x; i < E4; i += nblk * 256) {
        int4 d = d4[i];
        bool mx = (d.x >= nlo) & (d.x < nhi);
        bool my = (d.y >= nlo) & (d.y < nhi);
        bool mz = (d.z >= nlo) & (d.z < nhi);
        bool mw = (d.w >= nlo) & (d.w < nhi);
        if (mx | my | mz | mw) {
            int4 s = s4[i];
            if (mx) col[atomicAdd(&cursor[d.x], 1)] = s.x;
            if (my) col[atomicAdd(&cursor[d.y], 1)] = s.y;
            if (mz) col[atomicAdd(&cursor[d.z], 1)] = s.z;
            if (mw) col[atomicAdd(&cursor[d.w], 1)] = s.w;
        }
    }
    if (blockIdx.x == 0) {
        for (int e = (E4 << 2) + threadIdx.x; e < E; e += 256) {
            int d = edst[e];
            col[atomicAdd(&cursor[d], 1)] = esrc[e];
        }
    }
}

// ---------------------------------------------------------------------------
// Per-layer kernels
// ---------------------------------------------------------------------------
__device__ __forceinline__ ushort f2bf(float x) {
    uint u = __float_as_uint(x);
    u += 0x7fffu + ((u >> 16) & 1u); // RNE
    return (ushort)(u >> 16);
}
__device__ __forceinline__ float bflo(uint u) { return __uint_as_float(u << 16); }
__device__ __forceinline__ float bfhi(uint u) { return __uint_as_float(u & 0xffff0000u); }

// Register-blocked GEMM: block = 128 rows x 64 cols, thread = 8x4 outputs.
// out_bf16[r][j] = dinv[r] * sum_k act(in[r][k]) * W[k][j]; act = BN affine+relu (BN path).
// in_t staged transposed [k][row] so k-loop reads are b128, 2-way-or-free banks.
template <bool BN>
__global__ __launch_bounds__(256) void gemm_kernel(const float* __restrict__ inF,
                                                   const ushort* __restrict__ inB,
                                                   const float* __restrict__ W,
                                                   const float* __restrict__ bnp, // scale[64],shift[64]
                                                   const float* __restrict__ dinv,
                                                   ushort* __restrict__ outb, int N) {
    __shared__ float in_t[D][128]; // 32 KB, [k][row]
    __shared__ float Wl[D][D];     // 16 KB, [k][col]
    int t = threadIdx.x;
    for (int i = t; i < D * D / 4; i += 256)
        ((float4*)&Wl[0][0])[i] = ((const float4*)W)[i];

    int r = t >> 1;               // 0..127
    int fbase = (t & 1) * 32;
    int grow = blockIdx.x * 128 + r;
    if (BN) {
        if (grow < N) {
            const uint* src = (const uint*)(inB + (size_t)grow * D + fbase);
#pragma unroll
            for (int j = 0; j < 16; ++j) {
                uint u = src[j];
                int f = fbase + 2 * j;
                in_t[f][r]     = fmaxf(fmaf(bflo(u), bnp[f],     bnp[64 + f]),     0.f);
                in_t[f + 1][r] = fmaxf(fmaf(bfhi(u), bnp[f + 1], bnp[64 + f + 1]), 0.f);
            }
        } else {
#pragma unroll
            for (int j = 0; j < 32; ++j) in_t[fbase + j][r] = 0.f;
        }
    } else {
        if (grow < N) {
            const float4* src = (const float4*)(inF + (size_t)grow * D + fbase);
#pragma unroll
            for (int j = 0; j < 8; ++j) {
                float4 v = src[j];
                int f = fbase + 4 * j;
                in_t[f][r] = v.x; in_t[f + 1][r] = v.y; in_t[f + 2][r] = v.z; in_t[f + 3][r] = v.w;
            }
        } else {
#pragma unroll
            for (int j = 0; j < 32; ++j) in_t[fbase + j][r] = 0.f;
        }
    }
    __syncthreads();

    int rg = t & 15;  // rows 8*rg .. 8*rg+7
    int cg = t >> 4;  // cols 4*cg .. 4*cg+3
    float acc[8][4];
#pragma unroll
    for (int i = 0; i < 8; ++i)
#pragma unroll
        for (int j = 0; j < 4; ++j) acc[i][j] = 0.f;

#pragma unroll 8
    for (int k = 0; k < D; ++k) {
        float4 a0 = *(const float4*)&in_t[k][8 * rg];
        float4 a1 = *(const float4*)&in_t[k][8 * rg + 4];
        float4 b  = *(const float4*)&Wl[k][4 * cg];
        float ar[8] = {a0.x, a0.y, a0.z, a0.w, a1.x, a1.y, a1.z, a1.w};
        float br[4] = {b.x, b.y, b.z, b.w};
#pragma unroll
        for (int i = 0; i < 8; ++i)
#pragma unroll
            for (int j = 0; j < 4; ++j)
                acc[i][j] = fmaf(ar[i], br[j], acc[i][j]);
    }

#pragma unroll
    for (int i = 0; i < 8; ++i) {
        int row = blockIdx.x * 128 + 8 * rg + i;
        if (row < N) {
            float dn = dinv[row];
            uint2 pk;
            pk.x = ((uint)f2bf(acc[i][1] * dn) << 16) | (uint)f2bf(acc[i][0] * dn);
            pk.y = ((uint)f2bf(acc[i][3] * dn) << 16) | (uint)f2bf(acc[i][2] * dn);
            *(uint2*)(outb + (size_t)row * D + 4 * cg) = pk;
        }
    }
}

// 2 nodes per wave iteration; two 32-lane halves own alternate edges, unroll 8 per
// half per node -> up to 32 gathers in flight. lane covers features (2j,2j+1).
// outB[n] (bf16 pair) = dinv[n] * (hWs[n] + sum_src hWs[src]); fused BN stats.
__global__ __launch_bounds__(256) void agg_kernel(const ushort* __restrict__ hWs,
                                                  const int* __restrict__ rowptr,
                                                  const int* __restrict__ col,
                                                  const float* __restrict__ dinv,
                                                  uint* __restrict__ outB,
                                                  float* __restrict__ stats, int N) {
    const uint* hw32 = (const uint*)hWs;
    int lane = threadIdx.x & 63;
    int wv   = threadIdx.x >> 6;
    int half = lane >> 5;
    int j    = lane & 31;
    float sx = 0.f, sy = 0.f, qx = 0.f, qy = 0.f; // BN sum / sumsq partials (half 0 only)
    int gw = blockIdx.x * 4 + wv;
    int nw = gridDim.x * 4;
    for (int n0 = gw; n0 < N; n0 += 2 * nw) {
        int n1 = n0 + nw;
        bool h1 = n1 < N;
        int e0a = rowptr[n0], e1a = rowptr[n0 + 1];
        int e0b = 0, e1b = 0;
        if (h1) { e0b = rowptr[n1]; e1b = rowptr[n1 + 1]; }
        uint usa = hw32[(size_t)n0 * 32 + j];
        uint usb = h1 ? hw32[(size_t)n1 * 32 + j] : 0u;
        float ax = 0.f, ay = 0.f, bx = 0.f, by = 0.f;
        if (half == 0) { ax = bflo(usa); ay = bfhi(usa); bx = bflo(usb); by = bfhi(usb); }
        int ebA = e0a + half, ebB = e0b + half;
        int mA = max(e1a - 1, 0), mB = max(e1b - 1, 0);
        while (ebA < e1a || ebB < e1b) {
            int cc[16]; uint uu[16];
#pragma unroll
            for (int u = 0; u < 8; ++u) {
                int ia = ebA + 2 * u;
                cc[u] = col[ia <= mA ? ia : mA];
            }
#pragma unroll
            for (int u = 0; u < 8; ++u) {
                int ib = ebB + 2 * u;
                cc[8 + u] = col[ib <= mB ? ib : mB];
            }
#pragma unroll
            for (int u = 0; u < 16; ++u) uu[u] = hw32[(size_t)cc[u] * 32 + j];
#pragma unroll
            for (int u = 0; u < 8; ++u)
                if (ebA + 2 * u < e1a) { ax += bflo(uu[u]); ay += bfhi(uu[u]); }
#pragma unroll
            for (int u = 0; u < 8; ++u)
                if (ebB + 2 * u < e1b) { bx += bflo(uu[8 + u]); by += bfhi(uu[8 + u]); }
            ebA += 16; ebB += 16;
        }
        // combine the two halves
        ax += __shfl(ax, lane ^ 32); ay += __shfl(ay, lane ^ 32);
        bx += __shfl(bx, lane ^ 32); by += __shfl(by, lane ^ 32);
        float dna = dinv[n0];
        ax *= dna; ay *= dna;
        if (half == 0) {
            sx += ax; sy += ay; qx += ax * ax; qy += ay * ay;
            outB[(size_t)n0 * 32 + j] = ((uint)f2bf(ay) << 16) | (uint)f2bf(ax);
            if (h1) {
                float dnb = dinv[n1];
                bx *= dnb; by *= dnb;
                sx += bx; sy += by; qx += bx * bx; qy += by * by;
                outB[(size_t)n1 * 32 + j] = ((uint)f2bf(by) << 16) | (uint)f2bf(bx);
            }
        }
    }
    // block-level BN stats: features 0..63 sums, 64..127 sumsq -> atomics into stats[128]
    __shared__ float red[4][128];
    if (half == 0) {
        red[wv][2 * j]          = sx;
        red[wv][2 * j + 1]      = sy;
        red[wv][64 + 2 * j]     = qx;
        red[wv][64 + 2 * j + 1] = qy;
    }
    __syncthreads();
    int t = threadIdx.x;
    if (t < 128) {
        atomicAdd(&stats[t], red[0][t] + red[1][t] + red[2][t] + red[3][t]);
    }
}

// stats -> bnp (scale,shift); re-zero stats for next layer. one block, 64 threads.
__global__ void bn_finalize_kernel(float* __restrict__ stats,
                                   const float* __restrict__ gamma,
                                   const float* __restrict__ beta,
                                   int N, float* __restrict__ bnp) {
    int f = threadIdx.x; // 64 threads
    float invN = 1.f / (float)N;
    float s  = stats[f];
    float s2 = stats[64 + f];
    float mean = s * invN;
    float var  = s2 * invN - mean * mean;
    float sc   = gamma[f] * rsqrtf(var + BN_EPS);
    bnp[f]      = sc;
    bnp[64 + f] = beta[f] - mean * sc;
    stats[f] = 0.f;
    stats[64 + f] = 0.f;
}

// final: read bf16 pre-norm h, write fp32 BN+ReLU output
__global__ __launch_bounds__(256) void norm_relu_kernel(const uint* __restrict__ B,
                                                        const float* __restrict__ bnp,
                                                        float2* __restrict__ out, int n32) {
    int i = blockIdx.x * blockDim.x + threadIdx.x;
    if (i < n32) {
        int f2 = (i & 31) * 2;
        uint u = B[i];
        float a = fmaxf(fmaf(bflo(u), bnp[f2],     bnp[64 + f2]),     0.f);
        float b = fmaxf(fmaf(bfhi(u), bnp[f2 + 1], bnp[64 + f2 + 1]), 0.f);
        out[i] = make_float2(a, b);
    }
}

// ---------------------------------------------------------------------------
extern "C" void kernel_launch(void* const* d_in, const int* in_sizes, int n_in,
                              void* d_out, int out_size, void* d_ws, size_t ws_size,
                              hipStream_t stream) {
    const float* x      = (const float*)d_in[0];
    const int*   ei     = (const int*)d_in[1];
    const float* Ws     = (const float*)d_in[2];
    // d_in[3] = bs: cancels exactly under training-mode BatchNorm
    const float* gammas = (const float*)d_in[4];
    const float* betas  = (const float*)d_in[5];

    const int N = in_sizes[0] / D;           // 100000
    const int E = in_sizes[1] / 2;           // 1250000
    const int DEPTH = in_sizes[2] / (D * D); // 4

    const int* esrc = ei;
    const int* edst = ei + E;

    char* w = (char*)d_ws;
    size_t off = 0;
    auto alloc = [&](size_t bytes) {
        void* p = w + off;
        off = (off + bytes + 255) & ~(size_t)255;
        return p;
    };
    ushort* hWs    = (ushort*)alloc((size_t)N * D * sizeof(ushort)); // 12.8 MB bf16 (dinv-scaled h@W)
    uint*   B      = (uint*)alloc((size_t)N * (D / 2) * sizeof(uint)); // 12.8 MB bf16 pre-norm h
    int*    counts = (int*)alloc((size_t)N * sizeof(int));
    int*    rowptr = (int*)alloc((size_t)(N + 1) * sizeof(int));
    int*    cursor = (int*)alloc((size_t)(N + 1) * sizeof(int));
    float*  dinv   = (float*)alloc((size_t)N * sizeof(float));
    int*    col    = (int*)alloc((size_t)E * sizeof(int));
    int*    bsums  = (int*)alloc(512 * sizeof(int));
    int*    boff   = (int*)alloc(512 * sizeof(int));
    float*  stats  = (float*)alloc(128 * sizeof(float));
    float*  bnp    = (float*)alloc(128 * sizeof(float));

    const int nbScan = (N + 255) / 256; // 391

    // ---- degree + CSR ----
    hipMemsetAsync(counts, 0, (size_t)N * sizeof(int), stream);
    hipMemsetAsync(stats, 0, 128 * sizeof(float), stream);
    hist_kernel<<<1024, 256, 0, stream>>>(edst, E, N, counts);
    scan1_kernel<<<nbScan, 256, 0, stream>>>(counts, N, rowptr, bsums, dinv);
    scan2_kernel<<<1, 512, 0, stream>>>(bsums, nbScan, boff);
    scan3_kernel<<<nbScan, 256, 0, stream>>>(rowptr, boff, N, cursor);
    fill_kernel<<<1024, 256, 0, stream>>>(esrc, edst, E, N, cursor, col);

    // ---- layers ----
    const int gemmBlocks = (N + 127) / 128; // 782
    const int aggBlocks  = 2048;
    for (int l = 0; l < DEPTH; ++l) {
        const float* W = Ws + (size_t)l * D * D;
        if (l == 0)
            gemm_kernel<false><<<gemmBlocks, 256, 0, stream>>>(x, (const ushort*)B, W, bnp, dinv, hWs, N);
        else
            gemm_kernel<true><<<gemmBlocks, 256, 0, stream>>>(x, (const ushort*)B, W, bnp, dinv, hWs, N);
        agg_kernel<<<aggBlocks, 256, 0, stream>>>(hWs, rowptr, col, dinv, B, stats, N);
        bn_finalize_kernel<<<1, 64, 0, stream>>>(stats, gammas + l * D, betas + l * D, N, bnp);
    }
    // final BN + relu: bf16 B -> fp32 d_out
    norm_relu_kernel<<<(N * (D / 2) + 255) / 256, 256, 0, stream>>>(B, bnp, (float2*)d_out, N * (D / 2));
}

// Round 6
// 613.151 us; speedup vs baseline: 1.8963x; 1.0098x over previous
//
#include <hip/hip_runtime.h>

#define D 64
#define BN_EPS 1e-5f
#define NPART 8

// ---------------------------------------------------------------------------
// CSR build — hist/fill partitioned by dst range so each partition's scattered
// writes/atomics stay in one XCD's L2 (blockIdx%8 == XCD round-robin) and merge
// before writeback.
// ---------------------------------------------------------------------------
__global__ __launch_bounds__(256) void hist_kernel(const int* __restrict__ edst, int E, int N,
                                                   int* __restrict__ counts, uint* __restrict__ dummy) {
    // zero the dummy gather row (hWs row N) once per call
    if (blockIdx.x == gridDim.x - 1 && threadIdx.x < 32) dummy[threadIdx.x] = 0u;
    int part = blockIdx.x & (NPART - 1);
    int bIdx = blockIdx.x / NPART;
    int nblk = gridDim.x / NPART;
    int partN = (N + NPART - 1) / NPART;
    int nlo = part * partN;
    int nhi = min(N, nlo + partN);
    int E4 = E >> 2;
    const int4* d4 = (const int4*)edst;
    for (int i = bIdx * 256 + threadIdx.x; i < E4; i += nblk * 256) {
        int4 d = d4[i];
        if (d.x >= nlo && d.x < nhi) atomicAdd(&counts[d.x], 1);
        if (d.y >= nlo && d.y < nhi) atomicAdd(&counts[d.y], 1);
        if (d.z >= nlo && d.z < nhi) atomicAdd(&counts[d.z], 1);
        if (d.w >= nlo && d.w < nhi) atomicAdd(&counts[d.w], 1);
    }
    if (blockIdx.x == 0) {
        for (int e = (E4 << 2) + threadIdx.x; e < E; e += 256) atomicAdd(&counts[edst[e]], 1);
    }
}

// inclusive block scan of counts; rowptr[i+1] = incl(i) (pre-offset); bsums[b] = block total
// also emits dinv[i] = rsqrt(count+1)  (self loop included)
__global__ void scan1_kernel(const int* __restrict__ counts, int N,
                             int* __restrict__ rowptr, int* __restrict__ bsums,
                             float* __restrict__ dinv) {
    __shared__ int s[256];
    int i = blockIdx.x * 256 + threadIdx.x;
    int v = (i < N) ? counts[i] : 0;
    s[threadIdx.x] = v;
    __syncthreads();
    for (int off = 1; off < 256; off <<= 1) {
        int t = (threadIdx.x >= off) ? s[threadIdx.x - off] : 0;
        __syncthreads();
        s[threadIdx.x] += t;
        __syncthreads();
    }
    if (i < N) {
        rowptr[i + 1] = s[threadIdx.x];
        dinv[i] = rsqrtf((float)(v + 1));
    }
    if (threadIdx.x == 255) bsums[blockIdx.x] = s[255];
}

__global__ void scan2_kernel(const int* __restrict__ bsums, int nb, int* __restrict__ boff) {
    __shared__ int s[512];
    int v = (threadIdx.x < nb) ? bsums[threadIdx.x] : 0;
    s[threadIdx.x] = v;
    __syncthreads();
    for (int off = 1; off < 512; off <<= 1) {
        int t = (threadIdx.x >= off) ? s[threadIdx.x - off] : 0;
        __syncthreads();
        s[threadIdx.x] += t;
        __syncthreads();
    }
    if (threadIdx.x < nb) boff[threadIdx.x] = s[threadIdx.x] - v; // exclusive
}

// apply block offsets; also seed cursor = final rowptr
__global__ void scan3_kernel(int* __restrict__ rowptr, const int* __restrict__ boff, int N,
                             int* __restrict__ cursor) {
    int i = blockIdx.x * 256 + threadIdx.x;
    if (i == 0) { rowptr[0] = 0; cursor[0] = 0; }
    if (i < N) {
        int v = rowptr[i + 1] + boff[i >> 8];
        rowptr[i + 1] = v;
        if (i + 1 < N) cursor[i + 1] = v;
    }
}

__global__ __launch_bounds__(256) void fill_kernel(const int* __restrict__ esrc,
                                                   const int* __restrict__ edst, int E, int N,
                                                   int* __restrict__ cursor, int* __restrict__ col) {
    int part = blockIdx.x & (NPART - 1);
    int bIdx = blockIdx.x / NPART;
    int nblk = gridDim.x / NPART;
    int partN = (N + NPART - 1) / NPART;
    int nlo = part * partN;
    int nhi = min(N, nlo + partN);
    int E4 = E >> 2;
    const int4* d4 = (const int4*)edst;
    const int4* s4 = (const int4*)esrc;
    for (int i = bIdx * 256 + threadIdx.x; i < E4; i += nblk * 256) {
        int4 d = d4[i];
        bool mx = (d.x >= nlo) & (d.x < nhi);
        bool my = (d.y >= nlo) & (d.y < nhi);
        bool mz = (d.z >= nlo) & (d.z < nhi);
        bool mw = (d.w >= nlo) & (d.w < nhi);
        if (mx | my | mz | mw) {
            int4 s = s4[i];
            if (mx) col[atomicAdd(&cursor[d.x], 1)] = s.x;
            if (my) col[atomicAdd(&cursor[d.y], 1)] = s.y;
            if (mz) col[atomicAdd(&cursor[d.z], 1)] = s.z;
            if (mw) col[atomicAdd(&cursor[d.w], 1)] = s.w;
        }
    }
    if (blockIdx.x == 0) {
        for (int e = (E4 << 2) + threadIdx.x; e < E; e += 256) {
            int d = edst[e];
            col[atomicAdd(&cursor[d], 1)] = esrc[e];
        }
    }
}

// ---------------------------------------------------------------------------
// Per-layer kernels
// ---------------------------------------------------------------------------
__device__ __forceinline__ ushort f2bf(float x) {
    uint u = __float_as_uint(x);
    u += 0x7fffu + ((u >> 16) & 1u); // RNE
    return (ushort)(u >> 16);
}
__device__ __forceinline__ float bflo(uint u) { return __uint_as_float(u << 16); }
__device__ __forceinline__ float bfhi(uint u) { return __uint_as_float(u & 0xffff0000u); }

// Register-blocked GEMM: block = 128 rows x 64 cols, thread = 8x4 outputs.
// out_bf16[r][j] = dinv[r] * sum_k act(in[r][k]) * W[k][j]; act = BN affine+relu (BN path),
// with the BN scale/shift computed in-block from the previous layer's raw stats.
template <bool BN>
__global__ __launch_bounds__(256) void gemm_kernel(const float* __restrict__ inF,
                                                   const ushort* __restrict__ inB,
                                                   const float* __restrict__ W,
                                                   const float* __restrict__ stats, // prev layer sum/sumsq
                                                   const float* __restrict__ gamma,
                                                   const float* __restrict__ beta,
                                                   const float* __restrict__ dinv,
                                                   ushort* __restrict__ outb, int N) {
    __shared__ float in_t[D][128]; // 32 KB, [k][row]
    __shared__ float Wl[D][D];     // 16 KB, [k][col]
    __shared__ float bnl[128];
    int t = threadIdx.x;
    if (BN) {
        if (t < 64) {
            float invN = 1.f / (float)N;
            float mean = stats[t] * invN;
            float var  = stats[64 + t] * invN - mean * mean;
            float sc   = gamma[t] * rsqrtf(var + BN_EPS);
            bnl[t]      = sc;
            bnl[64 + t] = beta[t] - mean * sc;
        }
        __syncthreads();
    }
    for (int i = t; i < D * D / 4; i += 256)
        ((float4*)&Wl[0][0])[i] = ((const float4*)W)[i];

    int r = t >> 1;               // 0..127
    int fbase = (t & 1) * 32;
    int grow = blockIdx.x * 128 + r;
    if (BN) {
        if (grow < N) {
            const uint* src = (const uint*)(inB + (size_t)grow * D + fbase);
#pragma unroll
            for (int j = 0; j < 16; ++j) {
                uint u = src[j];
                int f = fbase + 2 * j;
                in_t[f][r]     = fmaxf(fmaf(bflo(u), bnl[f],     bnl[64 + f]),     0.f);
                in_t[f + 1][r] = fmaxf(fmaf(bfhi(u), bnl[f + 1], bnl[64 + f + 1]), 0.f);
            }
        } else {
#pragma unroll
            for (int j = 0; j < 32; ++j) in_t[fbase + j][r] = 0.f;
        }
    } else {
        if (grow < N) {
            const float4* src = (const float4*)(inF + (size_t)grow * D + fbase);
#pragma unroll
            for (int j = 0; j < 8; ++j) {
                float4 v = src[j];
                int f = fbase + 4 * j;
                in_t[f][r] = v.x; in_t[f + 1][r] = v.y; in_t[f + 2][r] = v.z; in_t[f + 3][r] = v.w;
            }
        } else {
#pragma unroll
            for (int j = 0; j < 32; ++j) in_t[fbase + j][r] = 0.f;
        }
    }
    __syncthreads();

    int rg = t & 15;  // rows 8*rg .. 8*rg+7
    int cg = t >> 4;  // cols 4*cg .. 4*cg+3
    float acc[8][4];
#pragma unroll
    for (int i = 0; i < 8; ++i)
#pragma unroll
        for (int j = 0; j < 4; ++j) acc[i][j] = 0.f;

#pragma unroll 8
    for (int k = 0; k < D; ++k) {
        float4 a0 = *(const float4*)&in_t[k][8 * rg];
        float4 a1 = *(const float4*)&in_t[k][8 * rg + 4];
        float4 b  = *(const float4*)&Wl[k][4 * cg];
        float ar[8] = {a0.x, a0.y, a0.z, a0.w, a1.x, a1.y, a1.z, a1.w};
        float br[4] = {b.x, b.y, b.z, b.w};
#pragma unroll
        for (int i = 0; i < 8; ++i)
#pragma unroll
            for (int j = 0; j < 4; ++j)
                acc[i][j] = fmaf(ar[i], br[j], acc[i][j]);
    }

#pragma unroll
    for (int i = 0; i < 8; ++i) {
        int row = blockIdx.x * 128 + 8 * rg + i;
        if (row < N) {
            float dn = dinv[row];
            uint2 pk;
            pk.x = ((uint)f2bf(acc[i][1] * dn) << 16) | (uint)f2bf(acc[i][0] * dn);
            pk.y = ((uint)f2bf(acc[i][3] * dn) << 16) | (uint)f2bf(acc[i][2] * dn);
            *(uint2*)(outb + (size_t)row * D + 4 * cg) = pk;
        }
    }
}

// Wave = 1 node; 4 groups of 16 lanes; lane owns features 4j..4j+3 (uint2 = 8 B).
// Each gather instruction fetches 4 rows (512 B); unroll 8 -> 32 rows in flight/wave.
// OOB edge slots gather the zero dummy row (index N). Cross-group combine = 2 shfl_xor.
// outB[n] (bf16 x4) = dinv[n] * (hWs[n] + sum_src hWs[src]); fused BN stats -> atomics.
__global__ __launch_bounds__(256) void agg_kernel(const ushort* __restrict__ hWs,
                                                  const int* __restrict__ rowptr,
                                                  const int* __restrict__ col,
                                                  const float* __restrict__ dinv,
                                                  uint2* __restrict__ outB,
                                                  float* __restrict__ stats, int N) {
    const uint2* hw64 = (const uint2*)hWs; // row stride = 16 uint2
    int t = threadIdx.x;
    int lane = t & 63;
    int wv   = t >> 6;       // 0..3
    int g    = lane >> 4;    // group 0..3
    int j    = lane & 15;    // feature quad: 4j..4j+3
    float s[4] = {0.f, 0.f, 0.f, 0.f}, q[4] = {0.f, 0.f, 0.f, 0.f};
    int gw = blockIdx.x * 4 + wv;
    int nw = gridDim.x * 4;
    for (int n = gw; n < N; n += nw) {
        int e0 = rowptr[n], e1 = rowptr[n + 1];
        float a[4] = {0.f, 0.f, 0.f, 0.f};
        uint2 us = hw64[(size_t)n * 16 + j];
        if (g == 0) { a[0] = bflo(us.x); a[1] = bfhi(us.x); a[2] = bflo(us.y); a[3] = bfhi(us.y); }
        int m = e1 - 1;
        for (int eb = e0 + g; eb < e1; eb += 32) {
            int cc[8];
            uint2 uu[8];
#pragma unroll
            for (int u = 0; u < 8; ++u) {
                int e = eb + 4 * u;
                bool ok = e < e1;
                int c = col[ok ? e : m];
                cc[u] = ok ? c : N; // dummy zero row when past end
            }
#pragma unroll
            for (int u = 0; u < 8; ++u) uu[u] = hw64[(size_t)cc[u] * 16 + j];
#pragma unroll
            for (int u = 0; u < 8; ++u) {
                a[0] += bflo(uu[u].x); a[1] += bfhi(uu[u].x);
                a[2] += bflo(uu[u].y); a[3] += bfhi(uu[u].y);
            }
        }
#pragma unroll
        for (int k = 0; k < 4; ++k) {
            a[k] += __shfl(a[k], lane ^ 16);
            a[k] += __shfl(a[k], lane ^ 32);
        }
        if (g == 0) {
            float dn = dinv[n];
#pragma unroll
            for (int k = 0; k < 4; ++k) { a[k] *= dn; s[k] += a[k]; q[k] += a[k] * a[k]; }
            uint2 pk;
            pk.x = ((uint)f2bf(a[1]) << 16) | (uint)f2bf(a[0]);
            pk.y = ((uint)f2bf(a[3]) << 16) | (uint)f2bf(a[2]);
            outB[(size_t)n * 16 + j] = pk;
        }
    }
    // block-level BN stats: features 0..63 sums, 64..127 sumsq -> atomics into stats[128]
    __shared__ float red[4][128];
    if (g == 0) {
#pragma unroll
        for (int k = 0; k < 4; ++k) {
            red[wv][4 * j + k]      = s[k];
            red[wv][64 + 4 * j + k] = q[k];
        }
    }
    __syncthreads();
    if (t < 128) {
        atomicAdd(&stats[t], red[0][t] + red[1][t] + red[2][t] + red[3][t]);
    }
}

// final: read bf16 pre-norm h, apply BN (computed in-block from stats) + ReLU, write fp32
__global__ __launch_bounds__(256) void norm_relu_kernel(const uint* __restrict__ B,
                                                        const float* __restrict__ stats,
                                                        const float* __restrict__ gamma,
                                                        const float* __restrict__ beta,
                                                        int N, float2* __restrict__ out, int n32) {
    __shared__ float bnl[128];
    int t = threadIdx.x;
    if (t < 64) {
        float invN = 1.f / (float)N;
        float mean = stats[t] * invN;
        float var  = stats[64 + t] * invN - mean * mean;
        float sc   = gamma[t] * rsqrtf(var + BN_EPS);
        bnl[t]      = sc;
        bnl[64 + t] = beta[t] - mean * sc;
    }
    __syncthreads();
    int i = blockIdx.x * 256 + t;
    if (i < n32) {
        int f2 = (i & 31) * 2;
        uint u = B[i];
        float a = fmaxf(fmaf(bflo(u), bnl[f2],     bnl[64 + f2]),     0.f);
        float b = fmaxf(fmaf(bfhi(u), bnl[f2 + 1], bnl[64 + f2 + 1]), 0.f);
        out[i] = make_float2(a, b);
    }
}

// ---------------------------------------------------------------------------
extern "C" void kernel_launch(void* const* d_in, const int* in_sizes, int n_in,
                              void* d_out, int out_size, void* d_ws, size_t ws_size,
                              hipStream_t stream) {
    const float* x      = (const float*)d_in[0];
    const int*   ei     = (const int*)d_in[1];
    const float* Ws     = (const float*)d_in[2];
    // d_in[3] = bs: cancels exactly under training-mode BatchNorm
    const float* gammas = (const float*)d_in[4];
    const float* betas  = (const float*)d_in[5];

    const int N = in_sizes[0] / D;           // 100000
    const int E = in_sizes[1] / 2;           // 1250000
    const int DEPTH = in_sizes[2] / (D * D); // 4

    const int* esrc = ei;
    const int* edst = ei + E;

    char* w = (char*)d_ws;
    size_t off = 0;
    auto alloc = [&](size_t bytes) {
        void* p = w + off;
        off = (off + bytes + 255) & ~(size_t)255;
        return p;
    };
    ushort* hWs    = (ushort*)alloc((size_t)(N + 1) * D * sizeof(ushort)); // +1 dummy zero row
    uint2*  B      = (uint2*)alloc((size_t)N * (D / 4) * sizeof(uint2));   // bf16 pre-norm h
    int*    counts = (int*)alloc((size_t)N * sizeof(int));                 // | contiguous with
    float*  stats  = (float*)alloc(4 * 128 * sizeof(float));               // | per-layer stats
    int*    rowptr = (int*)alloc((size_t)(N + 1) * sizeof(int));
    int*    cursor = (int*)alloc((size_t)(N + 1) * sizeof(int));
    float*  dinv   = (float*)alloc((size_t)N * sizeof(float));
    int*    col    = (int*)alloc((size_t)E * sizeof(int));
    int*    bsums  = (int*)alloc(512 * sizeof(int));
    int*    boff   = (int*)alloc(512 * sizeof(int));

    const int nbScan = (N + 255) / 256; // 391

    // single memset covers counts + (alignment pad) + stats
    size_t zbytes = (char*)(stats + 4 * 128) - (char*)counts;
    hipMemsetAsync(counts, 0, zbytes, stream);

    // ---- degree + CSR ----
    hist_kernel<<<1024, 256, 0, stream>>>(edst, E, N, counts, (uint*)(hWs + (size_t)N * D));
    scan1_kernel<<<nbScan, 256, 0, stream>>>(counts, N, rowptr, bsums, dinv);
    scan2_kernel<<<1, 512, 0, stream>>>(bsums, nbScan, boff);
    scan3_kernel<<<nbScan, 256, 0, stream>>>(rowptr, boff, N, cursor);
    fill_kernel<<<1024, 256, 0, stream>>>(esrc, edst, E, N, cursor, col);

    // ---- layers ----
    const int gemmBlocks = (N + 127) / 128; // 782
    const int aggBlocks  = 2048;
    for (int l = 0; l < DEPTH; ++l) {
        const float* W = Ws + (size_t)l * D * D;
        if (l == 0)
            gemm_kernel<false><<<gemmBlocks, 256, 0, stream>>>(x, (const ushort*)B, W,
                stats, gammas, betas, dinv, hWs, N);
        else
            gemm_kernel<true><<<gemmBlocks, 256, 0, stream>>>(x, (const ushort*)B, W,
                stats + (size_t)(l - 1) * 128, gammas + (l - 1) * D, betas + (l - 1) * D,
                dinv, hWs, N);
        agg_kernel<<<aggBlocks, 256, 0, stream>>>(hWs, rowptr, col, dinv, B,
                                                  stats + (size_t)l * 128, N);
    }
    // final BN + relu: bf16 B -> fp32 d_out
    norm_relu_kernel<<<(N * (D / 2) + 255) / 256, 256, 0, stream>>>((const uint*)B,
        stats + (size_t)(DEPTH - 1) * 128, gammas + (DEPTH - 1) * D, betas + (DEPTH - 1) * D,
        N, (float2*)d_out, N * (D / 2));
}

// Round 8
// 587.391 us; speedup vs baseline: 1.9794x; 1.0439x over previous
//
#include <hip/hip_runtime.h>

#define D 64
#define BN_EPS 1e-5f
#define NPART 8

// ---------------------------------------------------------------------------
// CSR build — hist/fill partitioned by dst range so each partition's scattered
// writes/atomics stay in one XCD's L2 (blockIdx%8 == XCD round-robin) and merge
// before writeback.
// ---------------------------------------------------------------------------
__global__ __launch_bounds__(256) void hist_kernel(const int* __restrict__ edst, int E, int N,
                                                   int* __restrict__ counts, uint* __restrict__ hwBase) {
    // zero the two dummy gather half-rows (row N of each half, 64 B each)
    if (blockIdx.x == gridDim.x - 1 && threadIdx.x < 32) {
        int t = threadIdx.x;
        size_t idx = (t < 16) ? ((size_t)N * 16 + t)
                              : ((size_t)(2 * N + 1) * 16 + (t - 16));
        hwBase[idx] = 0u;
    }
    int part = blockIdx.x & (NPART - 1);
    int bIdx = blockIdx.x / NPART;
    int nblk = gridDim.x / NPART;
    int partN = (N + NPART - 1) / NPART;
    int nlo = part * partN;
    int nhi = min(N, nlo + partN);
    int E4 = E >> 2;
    const int4* d4 = (const int4*)edst;
    for (int i = bIdx * 256 + threadIdx.x; i < E4; i += nblk * 256) {
        int4 d = d4[i];
        if (d.x >= nlo && d.x < nhi) atomicAdd(&counts[d.x], 1);
        if (d.y >= nlo && d.y < nhi) atomicAdd(&counts[d.y], 1);
        if (d.z >= nlo && d.z < nhi) atomicAdd(&counts[d.z], 1);
        if (d.w >= nlo && d.w < nhi) atomicAdd(&counts[d.w], 1);
    }
    if (blockIdx.x == 0) {
        for (int e = (E4 << 2) + threadIdx.x; e < E; e += 256) atomicAdd(&counts[edst[e]], 1);
    }
}

// inclusive block scan of counts; rowptr[i+1] = incl(i) (pre-offset); bsums[b] = block total
// also emits dinv[i] = rsqrt(count+1)  (self loop included)
__global__ void scan1_kernel(const int* __restrict__ counts, int N,
                             int* __restrict__ rowptr, int* __restrict__ bsums,
                             float* __restrict__ dinv) {
    __shared__ int s[256];
    int i = blockIdx.x * 256 + threadIdx.x;
    int v = (i < N) ? counts[i] : 0;
    s[threadIdx.x] = v;
    __syncthreads();
    for (int off = 1; off < 256; off <<= 1) {
        int t = (threadIdx.x >= off) ? s[threadIdx.x - off] : 0;
        __syncthreads();
        s[threadIdx.x] += t;
        __syncthreads();
    }
    if (i < N) {
        rowptr[i + 1] = s[threadIdx.x];
        dinv[i] = rsqrtf((float)(v + 1));
    }
    if (threadIdx.x == 255) bsums[blockIdx.x] = s[255];
}

__global__ void scan2_kernel(const int* __restrict__ bsums, int nb, int* __restrict__ boff) {
    __shared__ int s[512];
    int v = (threadIdx.x < nb) ? bsums[threadIdx.x] : 0;
    s[threadIdx.x] = v;
    __syncthreads();
    for (int off = 1; off < 512; off <<= 1) {
        int t = (threadIdx.x >= off) ? s[threadIdx.x - off] : 0;
        __syncthreads();
        s[threadIdx.x] += t;
        __syncthreads();
    }
    if (threadIdx.x < nb) boff[threadIdx.x] = s[threadIdx.x] - v; // exclusive
}

// apply block offsets; also seed cursor = final rowptr
__global__ void scan3_kernel(int* __restrict__ rowptr, const int* __restrict__ boff, int N,
                             int* __restrict__ cursor) {
    int i = blockIdx.x * 256 + threadIdx.x;
    if (i == 0) { rowptr[0] = 0; cursor[0] = 0; }
    if (i < N) {
        int v = rowptr[i + 1] + boff[i >> 8];
        rowptr[i + 1] = v;
        if (i + 1 < N) cursor[i + 1] = v;
    }
}

__global__ __launch_bounds__(256) void fill_kernel(const int* __restrict__ esrc,
                                                   const int* __restrict__ edst, int E, int N,
                                                   int* __restrict__ cursor, int* __restrict__ col) {
    int part = blockIdx.x & (NPART - 1);
    int bIdx = blockIdx.x / NPART;
    int nblk = gridDim.x / NPART;
    int partN = (N + NPART - 1) / NPART;
    int nlo = part * partN;
    int nhi = min(N, nlo + partN);
    int E4 = E >> 2;
    const int4* d4 = (const int4*)edst;
    const int4* s4 = (const int4*)esrc;
    for (int i = bIdx * 256 + threadIdx.x; i < E4; i += nblk * 256) {
        int4 d = d4[i];
        bool mx = (d.x >= nlo) & (d.x < nhi);
        bool my = (d.y >= nlo) & (d.y < nhi);
        bool mz = (d.z >= nlo) & (d.z < nhi);
        bool mw = (d.w >= nlo) & (d.w < nhi);
        if (mx | my | mz | mw) {
            int4 s = s4[i];
            if (mx) col[atomicAdd(&cursor[d.x], 1)] = s.x;
            if (my) col[atomicAdd(&cursor[d.y], 1)] = s.y;
            if (mz) col[atomicAdd(&cursor[d.z], 1)] = s.z;
            if (mw) col[atomicAdd(&cursor[d.w], 1)] = s.w;
        }
    }
    if (blockIdx.x == 0) {
        for (int e = (E4 << 2) + threadIdx.x; e < E; e += 256) {
            int d = edst[e];
            col[atomicAdd(&cursor[d], 1)] = esrc[e];
        }
    }
}

// ---------------------------------------------------------------------------
// Per-layer kernels
// ---------------------------------------------------------------------------
__device__ __forceinline__ ushort f2bf(float x) {
    uint u = __float_as_uint(x);
    u += 0x7fffu + ((u >> 16) & 1u); // RNE
    return (ushort)(u >> 16);
}
__device__ __forceinline__ float bflo(uint u) { return __uint_as_float(u << 16); }
__device__ __forceinline__ float bfhi(uint u) { return __uint_as_float(u & 0xffff0000u); }

// Register-blocked GEMM: block = 128 rows x 64 cols, thread = 8x4 outputs.
// Output layout = half-split bf16: hW[half][(N+1)][32], half-row = 64 B = 1 line.
// Input B (pre-norm h) is also half-split [2][N][32]. BN scale/shift computed
// in-block from the previous layer's raw stats.
template <bool BN>
__global__ __launch_bounds__(256) void gemm_kernel(const float* __restrict__ inF,
                                                   const ushort* __restrict__ inB,
                                                   const float* __restrict__ W,
                                                   const float* __restrict__ stats, // prev layer sum/sumsq
                                                   const float* __restrict__ gamma,
                                                   const float* __restrict__ beta,
                                                   const float* __restrict__ dinv,
                                                   ushort* __restrict__ outb, int N) {
    __shared__ float in_t[D][128]; // 32 KB, [k][row]
    __shared__ float Wl[D][D];     // 16 KB, [k][col]
    __shared__ float bnl[128];
    int t = threadIdx.x;
    if (BN) {
        if (t < 64) {
            float invN = 1.f / (float)N;
            float mean = stats[t] * invN;
            float var  = stats[64 + t] * invN - mean * mean;
            float sc   = gamma[t] * rsqrtf(var + BN_EPS);
            bnl[t]      = sc;
            bnl[64 + t] = beta[t] - mean * sc;
        }
        __syncthreads();
    }
    for (int i = t; i < D * D / 4; i += 256)
        ((float4*)&Wl[0][0])[i] = ((const float4*)W)[i];

    int r = t >> 1;               // 0..127
    int hh = t & 1;               // feature half
    int grow = blockIdx.x * 128 + r;
    if (BN) {
        if (grow < N) {
            const uint* src = (const uint*)(inB + ((size_t)hh * N + grow) * 32);
#pragma unroll
            for (int j = 0; j < 16; ++j) {
                uint u = src[j];
                int f = 32 * hh + 2 * j;
                in_t[f][r]     = fmaxf(fmaf(bflo(u), bnl[f],     bnl[64 + f]),     0.f);
                in_t[f + 1][r] = fmaxf(fmaf(bfhi(u), bnl[f + 1], bnl[64 + f + 1]), 0.f);
            }
        } else {
#pragma unroll
            for (int j = 0; j < 32; ++j) in_t[32 * hh + j][r] = 0.f;
        }
    } else {
        int fbase = hh * 32;
        if (grow < N) {
            const float4* src = (const float4*)(inF + (size_t)grow * D + fbase);
#pragma unroll
            for (int j = 0; j < 8; ++j) {
                float4 v = src[j];
                int f = fbase + 4 * j;
                in_t[f][r] = v.x; in_t[f + 1][r] = v.y; in_t[f + 2][r] = v.z; in_t[f + 3][r] = v.w;
            }
        } else {
#pragma unroll
            for (int j = 0; j < 32; ++j) in_t[fbase + j][r] = 0.f;
        }
    }
    __syncthreads();

    int rg = t & 15;  // rows 8*rg .. 8*rg+7
    int cg = t >> 4;  // cols 4*cg .. 4*cg+3
    float acc[8][4];
#pragma unroll
    for (int i = 0; i < 8; ++i)
#pragma unroll
        for (int j = 0; j < 4; ++j) acc[i][j] = 0.f;

#pragma unroll 8
    for (int k = 0; k < D; ++k) {
        float4 a0 = *(const float4*)&in_t[k][8 * rg];
        float4 a1 = *(const float4*)&in_t[k][8 * rg + 4];
        float4 b  = *(const float4*)&Wl[k][4 * cg];
        float ar[8] = {a0.x, a0.y, a0.z, a0.w, a1.x, a1.y, a1.z, a1.w};
        float br[4] = {b.x, b.y, b.z, b.w};
#pragma unroll
        for (int i = 0; i < 8; ++i)
#pragma unroll
            for (int j = 0; j < 4; ++j)
                acc[i][j] = fmaf(ar[i], br[j], acc[i][j]);
    }

    int oh = cg >> 3; // output feature half
    uint2* dst = (uint2*)(outb + (size_t)oh * (N + 1) * 32);
#pragma unroll
    for (int i = 0; i < 8; ++i) {
        int row = blockIdx.x * 128 + 8 * rg + i;
        if (row < N) {
            float dn = dinv[row];
            uint2 pk;
            pk.x = ((uint)f2bf(acc[i][1] * dn) << 16) | (uint)f2bf(acc[i][0] * dn);
            pk.y = ((uint)f2bf(acc[i][3] * dn) << 16) | (uint)f2bf(acc[i][2] * dn);
            dst[(size_t)row * 8 + (cg & 7)] = pk;
        }
    }
}

// Half-split aggregation. Block's feature half = (blockIdx%8)>>2 so XCDs 0-3 own
// half 0 and XCDs 4-7 own half 1 -> per-L2 random footprint 6.4 MB (was 12.8).
// Wave = 1 node; 8 groups x 8 lanes; lane owns 4 features (uint2 = 8 B); each
// gather instruction covers 8 rows x 64 B = one line per row; unroll 4 -> 32
// rows in flight. OOB slots read the zero dummy row (index N).
// out[half][n] = dinv[n] * (hW[half][n] + sum_src hW[half][src]); fused BN stats.
__global__ __launch_bounds__(256) void agg_kernel(const ushort* __restrict__ hW,
                                                  const int* __restrict__ rowptr,
                                                  const int* __restrict__ col,
                                                  const float* __restrict__ dinv,
                                                  ushort* __restrict__ outB,
                                                  float* __restrict__ stats, int N) {
    int part = blockIdx.x & 7;
    int h    = part >> 2;                               // feature half
    int bIdxH = (blockIdx.x >> 3) * 4 + (part & 3);     // block idx within half
    const uint2* hw2 = (const uint2*)(hW + (size_t)h * (N + 1) * 32);
    uint2* out2 = (uint2*)(outB + (size_t)h * N * 32);
    int t = threadIdx.x;
    int lane = t & 63;
    int wv   = t >> 6;       // 0..3
    int g    = lane >> 3;    // group 0..7 (edge slot)
    int j    = lane & 7;     // feature quad within half: 4j..4j+3
    float s[4] = {0.f, 0.f, 0.f, 0.f}, q[4] = {0.f, 0.f, 0.f, 0.f};
    int gw = bIdxH * 4 + wv;
    int nw = (gridDim.x >> 1) * 4; // waves per half
    for (int n = gw; n < N; n += nw) {
        int e0 = rowptr[n], e1 = rowptr[n + 1];
        float a[4] = {0.f, 0.f, 0.f, 0.f};
        if (g == 0) {
            uint2 us = hw2[(size_t)n * 8 + j];
            a[0] = bflo(us.x); a[1] = bfhi(us.x); a[2] = bflo(us.y); a[3] = bfhi(us.y);
        }
        int m = e1 - 1;
        for (int eb = e0; eb < e1; eb += 32) {
            int cc[4];
            uint2 uu[4];
#pragma unroll
            for (int u = 0; u < 4; ++u) {
                int e = eb + 8 * u + g;
                bool ok = e < e1;
                int c = col[ok ? e : m];
                cc[u] = ok ? c : N; // dummy zero row when past end
            }
#pragma unroll
            for (int u = 0; u < 4; ++u) uu[u] = hw2[(size_t)cc[u] * 8 + j];
#pragma unroll
            for (int u = 0; u < 4; ++u) {
                a[0] += bflo(uu[u].x); a[1] += bfhi(uu[u].x);
                a[2] += bflo(uu[u].y); a[3] += bfhi(uu[u].y);
            }
        }
#pragma unroll
        for (int k = 0; k < 4; ++k) {
            a[k] += __shfl(a[k], lane ^ 8);
            a[k] += __shfl(a[k], lane ^ 16);
            a[k] += __shfl(a[k], lane ^ 32);
        }
        if (g == 0) {
            float dn = dinv[n];
#pragma unroll
            for (int k = 0; k < 4; ++k) { a[k] *= dn; s[k] += a[k]; q[k] += a[k] * a[k]; }
            uint2 pk;
            pk.x = ((uint)f2bf(a[1]) << 16) | (uint)f2bf(a[0]);
            pk.y = ((uint)f2bf(a[3]) << 16) | (uint)f2bf(a[2]);
            out2[(size_t)n * 8 + j] = pk;
        }
    }
    // block-level BN stats for this half's 32 features -> atomics into stats[128]
    __shared__ float red[4][64];
    if (g == 0) {
#pragma unroll
        for (int k = 0; k < 4; ++k) {
            red[wv][4 * j + k]      = s[k];
            red[wv][32 + 4 * j + k] = q[k];
        }
    }
    __syncthreads();
    if (t < 64) {
        float v = red[0][t] + red[1][t] + red[2][t] + red[3][t];
        int f = t & 31;
        int base = (t < 32) ? 0 : 64; // sum block vs sumsq block
        atomicAdd(&stats[base + 32 * h + f], v);
    }
}

// final: read half-split bf16 pre-norm h, apply BN (computed in-block) + ReLU, write fp32
__global__ __launch_bounds__(256) void norm_relu_kernel(const uint* __restrict__ B32,
                                                        const float* __restrict__ stats,
                                                        const float* __restrict__ gamma,
                                                        const float* __restrict__ beta,
                                                        int N, float2* __restrict__ out) {
    __shared__ float bnl[128];
    int t = threadIdx.x;
    if (t < 64) {
        float invN = 1.f / (float)N;
        float mean = stats[t] * invN;
        float var  = stats[64 + t] * invN - mean * mean;
        float sc   = gamma[t] * rsqrtf(var + BN_EPS);
        bnl[t]      = sc;
        bnl[64 + t] = beta[t] - mean * sc;
    }
    __syncthreads();
    int i = blockIdx.x * 256 + t; // over [2][N][16] uints
    int total = N * 32;
    if (i < total) {
        int h = (i >= N * 16) ? 1 : 0;
        int rem = i - h * N * 16;
        int n = rem >> 4;
        int ju = rem & 15;
        int f2 = 32 * h + 2 * ju;
        uint u = B32[i];
        float a = fmaxf(fmaf(bflo(u), bnl[f2],     bnl[64 + f2]),     0.f);
        float b = fmaxf(fmaf(bfhi(u), bnl[f2 + 1], bnl[64 + f2 + 1]), 0.f);
        out[(size_t)n * 32 + 16 * h + ju] = make_float2(a, b);
    }
}

// ---------------------------------------------------------------------------
extern "C" void kernel_launch(void* const* d_in, const int* in_sizes, int n_in,
                              void* d_out, int out_size, void* d_ws, size_t ws_size,
                              hipStream_t stream) {
    const float* x      = (const float*)d_in[0];
    const int*   ei     = (const int*)d_in[1];
    const float* Ws     = (const float*)d_in[2];
    // d_in[3] = bs: cancels exactly under training-mode BatchNorm
    const float* gammas = (const float*)d_in[4];
    const float* betas  = (const float*)d_in[5];

    const int N = in_sizes[0] / D;           // 100000
    const int E = in_sizes[1] / 2;           // 1250000
    const int DEPTH = in_sizes[2] / (D * D); // 4

    const int* esrc = ei;
    const int* edst = ei + E;

    char* w = (char*)d_ws;
    size_t off = 0;
    auto alloc = [&](size_t bytes) {
        void* p = w + off;
        off = (off + bytes + 255) & ~(size_t)255;
        return p;
    };
    ushort* hW     = (ushort*)alloc((size_t)2 * (N + 1) * 32 * sizeof(ushort)); // half-split bf16 (+dummy rows)
    ushort* B      = (ushort*)alloc((size_t)2 * N * 32 * sizeof(ushort));       // half-split bf16 pre-norm h
    int*    counts = (int*)alloc((size_t)N * sizeof(int));                      // | contiguous with
    float*  stats  = (float*)alloc(4 * 128 * sizeof(float));                    // | per-layer stats
    int*    rowptr = (int*)alloc((size_t)(N + 1) * sizeof(int));
    int*    cursor = (int*)alloc((size_t)(N + 1) * sizeof(int));
    float*  dinv   = (float*)alloc((size_t)N * sizeof(float));
    int*    col    = (int*)alloc((size_t)E * sizeof(int));
    int*    bsums  = (int*)alloc(512 * sizeof(int));
    int*    boff   = (int*)alloc(512 * sizeof(int));

    const int nbScan = (N + 255) / 256; // 391

    // single memset covers counts + (alignment pad) + stats
    size_t zbytes = (char*)(stats + 4 * 128) - (char*)counts;
    hipMemsetAsync(counts, 0, zbytes, stream);

    // ---- degree + CSR ----
    hist_kernel<<<1024, 256, 0, stream>>>(edst, E, N, counts, (uint*)hW);
    scan1_kernel<<<nbScan, 256, 0, stream>>>(counts, N, rowptr, bsums, dinv);
    scan2_kernel<<<1, 512, 0, stream>>>(bsums, nbScan, boff);
    scan3_kernel<<<nbScan, 256, 0, stream>>>(rowptr, boff, N, cursor);
    fill_kernel<<<1024, 256, 0, stream>>>(esrc, edst, E, N, cursor, col);

    // ---- layers ----
    const int gemmBlocks = (N + 127) / 128; // 782
    const int aggBlocks  = 2048;
    for (int l = 0; l < DEPTH; ++l) {
        const float* W = Ws + (size_t)l * D * D;
        if (l == 0)
            gemm_kernel<false><<<gemmBlocks, 256, 0, stream>>>(x, B, W,
                stats, gammas, betas, dinv, hW, N);
        else
            gemm_kernel<true><<<gemmBlocks, 256, 0, stream>>>(x, B, W,
                stats + (size_t)(l - 1) * 128, gammas + (l - 1) * D, betas + (l - 1) * D,
                dinv, hW, N);
        agg_kernel<<<aggBlocks, 256, 0, stream>>>(hW, rowptr, col, dinv, B,
                                                  stats + (size_t)l * 128, N);
    }
    // final BN + relu: half-split bf16 B -> fp32 d_out
    norm_relu_kernel<<<(N * 32 + 255) / 256, 256, 0, stream>>>((const uint*)B,
        stats + (size_t)(DEPTH - 1) * 128, gammas + (DEPTH - 1) * D, betas + (DEPTH - 1) * D,
        N, (float2*)d_out);
}